// Round 3
// baseline (1010.545 us; speedup 1.0000x reference)
//
#include <hip/hip_runtime.h>
#include <hip/hip_cooperative_groups.h>
#include <math.h>

namespace cg = cooperative_groups;

#define LROWS 16384
#define HDIM  1024
#define MDIM  2048
#define RSQRT_D 0.08838834764831844f   // 1/sqrt(128)

// ---- workspace layout (float offsets). NOTHING needs pre-zeroing:
// every cell is fully written before it is read (no atomics anywhere).
#define OFF_W     0          // w[8][2048]      (P1, non-atomic full write)
#define OFF_BETA  16384      // beta[8]         (P1 block 0)
#define OFF_Z     16392      // Z[8]            (P4 block 0)
#define OFF_Q     16400      // q[1024]         (P0)
#define OFF_FEAT  17424      // feat[1024]      (P5)
#define OFF_Y     18448      // y[8][2048]      (P4)
#define OFF_ZP    34832      // zpart[512][8]   (P3 ch0 blocks)
#define OFF_S2    38928      // s2[2][16384][8] (P2 partial scores)
#define OFF_YBUF  301072     // ybuf[512][8][2048] (P3)  -> end 34.8 MB

__device__ __forceinline__ float dot4(float4 a, float4 b) {
  return a.x * b.x + a.y * b.y + a.z * b.z + a.w * b.w;
}
__device__ __forceinline__ void fma4(float4& acc, float s, float4 v) {
  acc.x = fmaf(s, v.x, acc.x); acc.y = fmaf(s, v.y, acc.y);
  acc.z = fmaf(s, v.z, acc.z); acc.w = fmaf(s, v.w, acc.w);
}
__device__ __forceinline__ void add4(float4& a, float4 v) {
  a.x += v.x; a.y += v.y; a.z += v.z; a.w += v.w;
}

// ---------- P0: q[bid] = x . Wq[bid,:] + bq[bid]  (block per output) ----------
__device__ __forceinline__ void p0_q(const float* __restrict__ x,
                                     const float* __restrict__ Wq,
                                     const float* __restrict__ bq,
                                     float* __restrict__ ws,
                                     float* lds, int bid, int tid) {
  int lane = tid & 63, wv = tid >> 6;
  const float4* x4 = (const float4*)x;
  const float4* w4 = (const float4*)(Wq + (size_t)bid * HDIM);
  float a = dot4(x4[tid], w4[tid]);
#pragma unroll
  for (int off = 32; off; off >>= 1) a += __shfl_xor(a, off);
  if (lane == 0) lds[wv] = a;
  __syncthreads();
  if (tid == 0) ws[OFF_Q + bid] = lds[0] + lds[1] + lds[2] + lds[3] + bq[bid];
}

// ---------- P1: w[n][m0..m0+1] full sums (non-atomic); block 0 adds beta ----------
// thread (n = tid>>5, g = tid&31): partial over k = g+32i, c = 8k+n.
__device__ __forceinline__ void p1_w(const float* __restrict__ Wk,
                                     const float* __restrict__ bk,
                                     float* __restrict__ ws,
                                     float* lds, int bid, int tid) {
  int n = tid >> 5, g = tid & 31;
  int m0 = bid * 2;
  const float* q = ws + OFF_Q;
  float ax = 0.f, ay = 0.f;
#pragma unroll
  for (int i = 0; i < 4; ++i) {
    int c = 8 * (g + 32 * i) + n;
    float2 wk = *(const float2*)(Wk + (size_t)c * MDIM + m0);
    float qc = q[c];
    ax = fmaf(qc, wk.x, ax);
    ay = fmaf(qc, wk.y, ay);
  }
#pragma unroll
  for (int off = 1; off < 32; off <<= 1) {
    ax += __shfl_xor(ax, off);
    ay += __shfl_xor(ay, off);
  }
  if (g == 0) *(float2*)(ws + OFF_W + n * MDIM + m0) = make_float2(ax, ay);
  if (bid == 0) {   // beta[n] = sum_{c%8==n} q[c]*bk[c]
    int nn = tid & 7;
    float b = 0.f;
#pragma unroll
    for (int i = 0; i < 4; ++i) {
      int c = tid + 256 * i;
      b = fmaf(q[c], bk[c], b);
    }
    b += __shfl_xor(b, 8); b += __shfl_xor(b, 16); b += __shfl_xor(b, 32);
    if ((tid & 63) < 8) lds[(tid >> 6) * 8 + nn] = b;
    __syncthreads();
    if (tid < 8)
      ws[OFF_BETA + tid] = lds[tid] + lds[8 + tid] + lds[16 + tid] + lds[24 + tid];
  }
}

// ---------- P2: partial scores. block (ch=bid&1, rg=bid>>1): 32 rows x 1024-col half.
// w half in LDS; per-n wlds read (live regs ~76 < 128, no spills); depth-1 prefetch.
__device__ __forceinline__ void p2_scores(const float* __restrict__ mem,
                                          float* __restrict__ ws,
                                          float* lds, int bid, int tid) {
  int lane = tid & 63, wv = tid >> 6;
  int ch = bid & 1, rg = bid >> 1;
  float4* wlds = (float4*)lds;     // [8][256] float4 = 32 KB
  const float4* wsrc = (const float4*)(ws + OFF_W + ch * 1024);
#pragma unroll
  for (int k = 0; k < 8; ++k) {
    int qi = k * 256 + tid;
    wlds[qi] = wsrc[(qi >> 8) * 512 + (qi & 255)];
  }
  __syncthreads();
#pragma unroll
  for (int pass = 0; pass < 2; ++pass) {
    int r0 = rg * 32 + pass * 16 + wv * 4;
    const float* base = mem + (size_t)r0 * MDIM + ch * 1024;
    float acc[4][8];
#pragma unroll
    for (int rr = 0; rr < 4; ++rr)
#pragma unroll
      for (int n = 0; n < 8; ++n) acc[rr][n] = 0.f;
    float4 mv[4], mvn[4];
#pragma unroll
    for (int rr = 0; rr < 4; ++rr)
      mv[rr] = *(const float4*)(base + rr * MDIM + lane * 4);
#pragma unroll
    for (int step = 0; step < 4; ++step) {
      int cq = step * 64 + lane;
      if (step < 3) {
#pragma unroll
        for (int rr = 0; rr < 4; ++rr)
          mvn[rr] = *(const float4*)(base + rr * MDIM + (cq + 64) * 4);
      }
#pragma unroll
      for (int n = 0; n < 8; ++n) {
        float4 wv4 = wlds[n * 256 + cq];
#pragma unroll
        for (int rr = 0; rr < 4; ++rr) {
          acc[rr][n] = fmaf(mv[rr].x, wv4.x, acc[rr][n]);
          acc[rr][n] = fmaf(mv[rr].y, wv4.y, acc[rr][n]);
          acc[rr][n] = fmaf(mv[rr].z, wv4.z, acc[rr][n]);
          acc[rr][n] = fmaf(mv[rr].w, wv4.w, acc[rr][n]);
        }
      }
#pragma unroll
      for (int rr = 0; rr < 4; ++rr) mv[rr] = mvn[rr];
    }
#pragma unroll
    for (int off = 1; off < 64; off <<= 1)
#pragma unroll
      for (int rr = 0; rr < 4; ++rr)
#pragma unroll
        for (int n = 0; n < 8; ++n)
          acc[rr][n] += __shfl_xor(acc[rr][n], off);
    if (lane == 0) {
      float* sdst = ws + OFF_S2 + (size_t)ch * 131072 + (size_t)r0 * 8;
#pragma unroll
      for (int rr = 0; rr < 4; ++rr)
#pragma unroll
        for (int n = 0; n < 8; ++n)
          sdst[rr * 8 + n] = acc[rr][n];
    }
  }
}

// ---------- P3: p = exp((s0+s1+beta)*rsqrtd); zpart; ybuf += p*mem (L3-hot) ----------
__device__ __forceinline__ void p3_wsum(const float* __restrict__ mem,
                                        float* __restrict__ ws,
                                        float* lds, int bid, int tid) {
  int lane = tid & 63, wv = tid >> 6;
  int ch = bid & 1, rc = bid >> 1;
  int r0 = rc * 32;
  float* pp = lds;          // 256 floats
  float* zz = lds + 256;    // 32
  {
    int n = tid & 7;
    int r = r0 + (tid >> 3);
    float s0 = ws[OFF_S2 + (size_t)r * 8 + n];
    float s1 = ws[OFF_S2 + 131072 + (size_t)r * 8 + n];
    float p = __expf((s0 + s1 + ws[OFF_BETA + n]) * RSQRT_D);
    pp[tid] = p;
    if (ch == 0) {
      float z = p;
      z += __shfl_xor(z, 8); z += __shfl_xor(z, 16); z += __shfl_xor(z, 32);
      if (lane < 8) zz[wv * 8 + lane] = z;
    }
  }
  __syncthreads();
  if (ch == 0 && tid < 8)
    ws[OFF_ZP + rc * 8 + tid] = zz[tid] + zz[8 + tid] + zz[16 + tid] + zz[24 + tid];

  float4 acc[8];
#pragma unroll
  for (int n = 0; n < 8; ++n) acc[n] = make_float4(0.f, 0.f, 0.f, 0.f);
  const float* base = mem + (size_t)r0 * MDIM + ch * 1024 + tid * 4;
  const float4* pp4 = (const float4*)pp;
#pragma unroll 4
  for (int r = 0; r < 32; ++r) {
    float4 mv = *(const float4*)(base + (size_t)r * MDIM);
    float4 pA = pp4[r * 2], pB = pp4[r * 2 + 1];   // broadcast
    fma4(acc[0], pA.x, mv); fma4(acc[1], pA.y, mv);
    fma4(acc[2], pA.z, mv); fma4(acc[3], pA.w, mv);
    fma4(acc[4], pB.x, mv); fma4(acc[5], pB.y, mv);
    fma4(acc[6], pB.z, mv); fma4(acc[7], pB.w, mv);
  }
  float* yb = ws + OFF_YBUF + (size_t)rc * 16384 + ch * 1024 + tid * 4;
#pragma unroll
  for (int n = 0; n < 8; ++n)
    *(float4*)(yb + n * MDIM) = acc[n];
}

// ---------- P4: y[quad] = sum_b ybuf[b][quad]; block 0 reduces Z ----------
__device__ __forceinline__ void p4_yred(float* __restrict__ ws,
                                        float* lds, int bid, int tid) {
  int lane = tid & 63, wv = tid >> 6;
  const float4* src = (const float4*)(ws + OFF_YBUF);
  int qd = bid * 4 + (tid & 3);
  int h = tid >> 2;                  // 0..63
  float4 a = make_float4(0.f, 0.f, 0.f, 0.f);
#pragma unroll
  for (int i = 0; i < 8; ++i)
    add4(a, src[(size_t)(h + 64 * i) * 4096 + qd]);
#pragma unroll
  for (int off = 4; off < 64; off <<= 1) {
    a.x += __shfl_xor(a.x, off);
    a.y += __shfl_xor(a.y, off);
    a.z += __shfl_xor(a.z, off);
    a.w += __shfl_xor(a.w, off);
  }
  float4* sq = (float4*)lds;         // 16 float4 (lds[0..63])
  if (lane < 4) sq[wv * 4 + lane] = a;
  __syncthreads();
  if (tid < 4) {
    float4 s = sq[tid];
    add4(s, sq[4 + tid]); add4(s, sq[8 + tid]); add4(s, sq[12 + tid]);
    ((float4*)(ws + OFF_Y))[bid * 4 + tid] = s;
  }
  if (bid == 0) {   // Z[n] = sum_rc zpart[rc][n]
    int n = tid & 7;
    float z = 0.f;
#pragma unroll
    for (int i = 0; i < 16; ++i)
      z += ws[OFF_ZP + ((tid >> 3) + 32 * i) * 8 + n];
    z += __shfl_xor(z, 8); z += __shfl_xor(z, 16); z += __shfl_xor(z, 32);
    float* zzz = lds + 64;
    if (lane < 8) zzz[wv * 8 + lane] = z;
    __syncthreads();
    if (tid < 8)
      ws[OFF_Z + tid] = zzz[tid] + zzz[8 + tid] + zzz[16 + tid] + zzz[24 + tid];
  }
}

// ---------- P5: feat[bid] = (y[n] . Wv[bid,:]) / Z[n] + bv[bid] ----------
__device__ __forceinline__ void p5_feat(const float* __restrict__ Wv,
                                        const float* __restrict__ bv,
                                        float* __restrict__ ws,
                                        float* lds, int bid, int tid) {
  int lane = tid & 63, wv = tid >> 6;
  int c = bid, n = c & 7;
  const float4* yb = (const float4*)(ws + OFF_Y + n * MDIM);
  const float4* wb = (const float4*)(Wv + (size_t)c * MDIM);
  float a = dot4(yb[tid], wb[tid]) + dot4(yb[tid + 256], wb[tid + 256]);
#pragma unroll
  for (int off = 32; off; off >>= 1) a += __shfl_xor(a, off);
  if (lane == 0) lds[wv] = a;
  __syncthreads();
  if (tid == 0)
    ws[OFF_FEAT + c] = (lds[0] + lds[1] + lds[2] + lds[3]) / ws[OFF_Z + n] + bv[c];
}

// ---------- P6: out[bid] = relu(x.Wo[bid,:1024] + feat.Wo[bid,1024:] + bo) ----------
__device__ __forceinline__ void p6_out(const float* __restrict__ x,
                                       const float* __restrict__ Wo,
                                       const float* __restrict__ bo,
                                       const float* __restrict__ ws,
                                       float* __restrict__ out,
                                       float* lds, int bid, int tid) {
  int lane = tid & 63, wv = tid >> 6;
  int j = bid;
  const float4* wb = (const float4*)(Wo + (size_t)j * 2048);
  const float4* x4 = (const float4*)x;
  const float4* f4 = (const float4*)(ws + OFF_FEAT);
  float a = dot4(x4[tid], wb[tid]) + dot4(f4[tid], wb[256 + tid]);
#pragma unroll
  for (int off = 32; off; off >>= 1) a += __shfl_xor(a, off);
  if (lane == 0) lds[wv] = a;
  __syncthreads();
  if (tid == 0)
    out[j] = fmaxf(lds[0] + lds[1] + lds[2] + lds[3] + bo[j], 0.f);
}

// ---------- mega: one cooperative dispatch, 1024 blocks (4/CU co-resident) ----------
__global__ __launch_bounds__(256, 4) void mega(const float* __restrict__ x,
                                               const float* __restrict__ mem,
                                               const float* __restrict__ Wq,
                                               const float* __restrict__ bq,
                                               const float* __restrict__ Wk,
                                               const float* __restrict__ bk,
                                               const float* __restrict__ Wv,
                                               const float* __restrict__ bv,
                                               const float* __restrict__ Wo,
                                               const float* __restrict__ bo,
                                               float* __restrict__ ws,
                                               float* __restrict__ out) {
  __shared__ __align__(16) float lds[8192];   // 32 KB -> exactly 4 blocks/CU
  cg::grid_group g = cg::this_grid();
  int bid = blockIdx.x, tid = threadIdx.x;
  p0_q(x, Wq, bq, ws, lds, bid, tid);
  g.sync();
  p1_w(Wk, bk, ws, lds, bid, tid);
  g.sync();
  p2_scores(mem, ws, lds, bid, tid);
  g.sync();
  p3_wsum(mem, ws, lds, bid, tid);
  g.sync();
  p4_yred(ws, lds, bid, tid);
  g.sync();
  p5_feat(Wv, bv, ws, lds, bid, tid);
  g.sync();
  p6_out(x, Wo, bo, ws, out, lds, bid, tid);
}

// ---------- fallback: same phases as 7 plain dispatches (if coop launch fails) ----------
__global__ __launch_bounds__(256) void f0(const float* x, const float* Wq,
                                          const float* bq, float* ws) {
  __shared__ __align__(16) float lds[8];
  p0_q(x, Wq, bq, ws, lds, blockIdx.x, threadIdx.x);
}
__global__ __launch_bounds__(256) void f1(const float* Wk, const float* bk, float* ws) {
  __shared__ __align__(16) float lds[32];
  p1_w(Wk, bk, ws, lds, blockIdx.x, threadIdx.x);
}
__global__ __launch_bounds__(256, 4) void f2(const float* mem, float* ws) {
  __shared__ __align__(16) float lds[8192];
  p2_scores(mem, ws, lds, blockIdx.x, threadIdx.x);
}
__global__ __launch_bounds__(256, 4) void f3(const float* mem, float* ws) {
  __shared__ __align__(16) float lds[288];
  p3_wsum(mem, ws, lds, blockIdx.x, threadIdx.x);
}
__global__ __launch_bounds__(256) void f4(float* ws) {
  __shared__ __align__(16) float lds[96];
  p4_yred(ws, lds, blockIdx.x, threadIdx.x);
}
__global__ __launch_bounds__(256) void f5(const float* Wv, const float* bv, float* ws) {
  __shared__ __align__(16) float lds[8];
  p5_feat(Wv, bv, ws, lds, blockIdx.x, threadIdx.x);
}
__global__ __launch_bounds__(256) void f6(const float* x, const float* Wo,
                                          const float* bo, const float* ws, float* out) {
  __shared__ __align__(16) float lds[8];
  p6_out(x, Wo, bo, ws, out, lds, blockIdx.x, threadIdx.x);
}

extern "C" void kernel_launch(void* const* d_in, const int* in_sizes, int n_in,
                              void* d_out, int out_size, void* d_ws, size_t ws_size,
                              hipStream_t stream) {
  const float* x   = (const float*)d_in[0];
  const float* mem = (const float*)d_in[1];
  const float* Wq  = (const float*)d_in[2];
  const float* bq  = (const float*)d_in[3];
  const float* Wk  = (const float*)d_in[4];
  const float* bk  = (const float*)d_in[5];
  const float* Wv  = (const float*)d_in[6];
  const float* bv  = (const float*)d_in[7];
  const float* Wo  = (const float*)d_in[8];
  const float* bo  = (const float*)d_in[9];
  float* ws  = (float*)d_ws;
  float* out = (float*)d_out;

  void* args[12] = {(void*)&x, (void*)&mem, (void*)&Wq, (void*)&bq,
                    (void*)&Wk, (void*)&bk, (void*)&Wv, (void*)&bv,
                    (void*)&Wo, (void*)&bo, (void*)&ws, (void*)&out};
  hipError_t err = hipLaunchCooperativeKernel(mega, dim3(1024), dim3(256),
                                              args, 0, stream);
  if (err != hipSuccess) {
    // fallback: identical math as 7 plain dispatches
    f0<<<1024, 256, 0, stream>>>(x, Wq, bq, ws);
    f1<<<1024, 256, 0, stream>>>(Wk, bk, ws);
    f2<<<1024, 256, 0, stream>>>(mem, ws);
    f3<<<1024, 256, 0, stream>>>(mem, ws);
    f4<<<1024, 256, 0, stream>>>(ws);
    f5<<<1024, 256, 0, stream>>>(Wv, bv, ws);
    f6<<<1024, 256, 0, stream>>>(x, Wo, bo, ws, out);
  }
}

// Round 4
// 273.914 us; speedup vs baseline: 3.6893x; 3.6893x over previous
//
#include <hip/hip_runtime.h>
#include <math.h>

#define LROWS 16384
#define HDIM  1024
#define MDIM  2048
#define RSQRT_D 0.08838834764831844f   // 1/sqrt(128)

// ---- workspace layout (float offsets) ----
// Only w needs zeroing (kw atomics); kq zeroes it. Everything else full-write.
#define OFF_W     0          // w[8][2048]      (kw, atomic accum; zeroed by kq)
#define OFF_BETA  16384      // beta[8]         (kw block 256, non-atomic)
#define OFF_Z     16392      // Z[8]            (ky block 0, non-atomic)
#define OFF_Q     16400      // q[1024]         (kq)
#define OFF_FEAT  17424      // feat[1024]      (kf)
#define OFF_Y     18448      // y[8][2048]      (ky)
#define OFF_ZP    34832      // zpart[512][8]   (kb ch0 blocks)
#define OFF_S2    38928      // s2[2][16384][8] (kA3 partial scores, 1 MB)
#define OFF_YBUF  301072     // ybuf[512][8][2048] (kb, 33.6 MB) -> end 34.8 MB

__device__ __forceinline__ float dot4(float4 a, float4 b) {
  return a.x * b.x + a.y * b.y + a.z * b.z + a.w * b.w;
}
__device__ __forceinline__ void fma4(float4& acc, float s, float4 v) {
  acc.x = fmaf(s, v.x, acc.x); acc.y = fmaf(s, v.y, acc.y);
  acc.z = fmaf(s, v.z, acc.z); acc.w = fmaf(s, v.w, acc.w);
}
__device__ __forceinline__ void add4(float4& a, float4 v) {
  a.x += v.x; a.y += v.y; a.z += v.z; a.w += v.w;
}

// ---- kq: q[j] = x.Wq[j,:] + bq[j] (wave per j); also zeroes w for kw's atomics ----
__global__ __launch_bounds__(256) void kq(const float* __restrict__ x,
                                          const float* __restrict__ Wq,
                                          const float* __restrict__ bq,
                                          float* __restrict__ ws) {
  int tid = threadIdx.x, lane = tid & 63;
  int j = blockIdx.x * 4 + (tid >> 6);
  const float4* xr = (const float4*)x;
  const float4* wr = (const float4*)(Wq + (size_t)j * HDIM);
  float acc = 0.f;
#pragma unroll
  for (int i = 0; i < 4; ++i) {
    int idx = i * 64 + lane;
    acc += dot4(xr[idx], wr[idx]);
  }
#pragma unroll
  for (int off = 32; off; off >>= 1) acc += __shfl_xor(acc, off);
  if (lane == 0) ws[OFF_Q + j] = acc + bq[j];
  // zero w slice: 16384 floats / 256 blocks = 64 per block
  if (tid < 64) ws[OFF_W + blockIdx.x * 64 + tid] = 0.f;
}

// ---- kw: w[n][m] += q[c]*Wk[c][m] (c-chunked atomics, grid 256);
//          block 256: beta[n] = sum_{c%8==n} q[c]*bk[c] (non-atomic) ----
__global__ __launch_bounds__(256) void kw(const float* __restrict__ Wk,
                                          const float* __restrict__ bk,
                                          float* __restrict__ ws) {
  __shared__ float lds[32];
  int tid = threadIdx.x;
  const float* q = ws + OFF_Q;
  if (blockIdx.x == 256) {   // beta block (proven in R3 mega, passed refcheck)
    float b = 0.f;
#pragma unroll
    for (int i = 0; i < 4; ++i) {
      int c = tid + 256 * i;
      b = fmaf(q[c], bk[c], b);
    }
    b += __shfl_xor(b, 8); b += __shfl_xor(b, 16); b += __shfl_xor(b, 32);
    if ((tid & 63) < 8) lds[(tid >> 6) * 8 + (tid & 7)] = b;
    __syncthreads();
    if (tid < 8)
      ws[OFF_BETA + tid] = lds[tid] + lds[8 + tid] + lds[16 + tid] + lds[24 + tid];
    return;
  }
  int mc = blockIdx.x & 7, cc = blockIdx.x >> 3;   // 8 m-chunks x 32 c-chunks
  int m = mc * 256 + tid;
  float acc[8];
#pragma unroll
  for (int n = 0; n < 8; ++n) acc[n] = 0.f;
  int c0 = cc * 32;
#pragma unroll
  for (int cb = 0; cb < 32; cb += 8) {
#pragma unroll
    for (int u = 0; u < 8; ++u)
      acc[u] = fmaf(q[c0 + cb + u], Wk[(size_t)(c0 + cb + u) * MDIM + m], acc[u]);
  }
#pragma unroll
  for (int n = 0; n < 8; ++n) atomicAdd(&ws[OFF_W + n * MDIM + m], acc[n]);
}

// ---- kA3: partial scores, wave-owns-8-rows, small live set (~70 VGPR).
// Grid 1024 = 512 rg (32 rows) x 2 col-halves. w half staged in LDS (32 KB).
// Per row: mv[4] in flight + mvn[4] next-row prefetch; 4x{8 ds_read_b128 + 32 FMA};
// 6-level butterfly; lane0 stores 32 B of s2 partials. No atomics.
__global__ __launch_bounds__(256, 4) void kA3(const float* __restrict__ mem,
                                              float* __restrict__ ws) {
  __shared__ float4 wlds[2048];   // w[n][c4] for this half, 32 KB
  int tid = threadIdx.x, lane = tid & 63, wv = tid >> 6;
  int ch = blockIdx.x & 1, rg = blockIdx.x >> 1;
  const float4* wsrc = (const float4*)(ws + OFF_W + ch * 1024);
#pragma unroll
  for (int k = 0; k < 8; ++k) {
    int qi = k * 256 + tid;
    wlds[qi] = wsrc[(qi >> 8) * 512 + (qi & 255)];   // row stride 2048 f = 512 f4
  }
  __syncthreads();

  int r0 = rg * 32 + wv * 8;                 // this wave's 8 rows
  const float* base = mem + (size_t)r0 * MDIM + ch * 1024;
  float* sbase = ws + OFF_S2 + (size_t)ch * 131072 + (size_t)r0 * 8;

  float4 mv[4], mvn[4];
#pragma unroll
  for (int i = 0; i < 4; ++i)
    mv[i] = *(const float4*)(base + (i * 64 + lane) * 4);

#pragma unroll
  for (int rl = 0; rl < 8; ++rl) {
    if (rl < 7) {   // prefetch next row while this row computes/reduces
#pragma unroll
      for (int i = 0; i < 4; ++i)
        mvn[i] = *(const float4*)(base + (size_t)(rl + 1) * MDIM + (i * 64 + lane) * 4);
    }
    float acc[8];
#pragma unroll
    for (int n = 0; n < 8; ++n) acc[n] = 0.f;
#pragma unroll
    for (int pass = 0; pass < 4; ++pass) {
      int cq = pass * 64 + lane;
#pragma unroll
      for (int n = 0; n < 8; ++n) {
        float4 w4 = wlds[n * 256 + cq];
        acc[n] = fmaf(mv[pass].x, w4.x, acc[n]);
        acc[n] = fmaf(mv[pass].y, w4.y, acc[n]);
        acc[n] = fmaf(mv[pass].z, w4.z, acc[n]);
        acc[n] = fmaf(mv[pass].w, w4.w, acc[n]);
      }
    }
#pragma unroll
    for (int off = 1; off < 64; off <<= 1)
#pragma unroll
      for (int n = 0; n < 8; ++n)
        acc[n] += __shfl_xor(acc[n], off);
    if (lane == 0) {
      float4* dst = (float4*)(sbase + rl * 8);
      dst[0] = make_float4(acc[0], acc[1], acc[2], acc[3]);
      dst[1] = make_float4(acc[4], acc[5], acc[6], acc[7]);
    }
#pragma unroll
    for (int i = 0; i < 4; ++i) mv[i] = mvn[i];
  }
}

// ---- kb: p = exp((s0+s1+beta)*rsqrtd); zpart (ch0); ybuf += p*mem (L3-hot).
// Grid 1024 = 512 rc (32 rows) x 2 col-halves. Proven body (R2 kB2 / R3 p3). ----
__global__ __launch_bounds__(256, 4) void kb(const float* __restrict__ mem,
                                             float* __restrict__ ws) {
  __shared__ __align__(16) float pp[256];  // p[32 rows][8 heads]
  __shared__ float zz[32];
  int tid = threadIdx.x, lane = tid & 63, wv = tid >> 6;
  int rc = blockIdx.x >> 1, ch = blockIdx.x & 1;
  int r0 = rc * 32;
  {
    int n = tid & 7;
    int r = r0 + (tid >> 3);
    float s0 = ws[OFF_S2 + (size_t)r * 8 + n];
    float s1 = ws[OFF_S2 + 131072 + (size_t)r * 8 + n];
    float p = __expf((s0 + s1 + ws[OFF_BETA + n]) * RSQRT_D);
    pp[tid] = p;
    if (ch == 0) {
      float z = p;
      z += __shfl_xor(z, 8); z += __shfl_xor(z, 16); z += __shfl_xor(z, 32);
      if (lane < 8) zz[wv * 8 + lane] = z;
    }
  }
  __syncthreads();
  if (ch == 0 && tid < 8)
    ws[OFF_ZP + rc * 8 + tid] = zz[tid] + zz[8 + tid] + zz[16 + tid] + zz[24 + tid];

  float4 acc[8];
#pragma unroll
  for (int n = 0; n < 8; ++n) acc[n] = make_float4(0.f, 0.f, 0.f, 0.f);
  const float* base = mem + (size_t)r0 * MDIM + ch * 1024 + tid * 4;
  const float4* pp4 = (const float4*)pp;
#pragma unroll 4
  for (int r = 0; r < 32; ++r) {
    float4 mv = *(const float4*)(base + (size_t)r * MDIM);
    float4 pA = pp4[r * 2], pB = pp4[r * 2 + 1];   // broadcast
    fma4(acc[0], pA.x, mv); fma4(acc[1], pA.y, mv);
    fma4(acc[2], pA.z, mv); fma4(acc[3], pA.w, mv);
    fma4(acc[4], pB.x, mv); fma4(acc[5], pB.y, mv);
    fma4(acc[6], pB.z, mv); fma4(acc[7], pB.w, mv);
  }
  float* yb = ws + OFF_YBUF + (size_t)rc * 16384 + ch * 1024 + tid * 4;
#pragma unroll
  for (int n = 0; n < 8; ++n)
    *(float4*)(yb + n * MDIM) = acc[n];
}

// ---- ky: y[quad] = sum_b ybuf[b][quad]; block 0 reduces Z. Grid 1024. ----
__global__ __launch_bounds__(256) void ky(float* __restrict__ ws) {
  __shared__ __align__(16) float lds[96];
  int tid = threadIdx.x, lane = tid & 63, wv = tid >> 6;
  int bid = blockIdx.x;
  const float4* src = (const float4*)(ws + OFF_YBUF);
  int qd = bid * 4 + (tid & 3);
  int h = tid >> 2;                  // 0..63
  float4 a = make_float4(0.f, 0.f, 0.f, 0.f);
#pragma unroll
  for (int i = 0; i < 8; ++i)
    add4(a, src[(size_t)(h + 64 * i) * 4096 + qd]);
#pragma unroll
  for (int off = 4; off < 64; off <<= 1) {
    a.x += __shfl_xor(a.x, off);
    a.y += __shfl_xor(a.y, off);
    a.z += __shfl_xor(a.z, off);
    a.w += __shfl_xor(a.w, off);
  }
  float4* sq = (float4*)lds;         // 16 float4
  if (lane < 4) sq[wv * 4 + lane] = a;
  __syncthreads();
  if (tid < 4) {
    float4 s = sq[tid];
    add4(s, sq[4 + tid]); add4(s, sq[8 + tid]); add4(s, sq[12 + tid]);
    ((float4*)(ws + OFF_Y))[bid * 4 + tid] = s;
  }
  if (bid == 0) {   // Z[n] = sum_rc zpart[rc][n]
    int n = tid & 7;
    float z = 0.f;
#pragma unroll
    for (int i = 0; i < 16; ++i)
      z += ws[OFF_ZP + ((tid >> 3) + 32 * i) * 8 + n];
    z += __shfl_xor(z, 8); z += __shfl_xor(z, 16); z += __shfl_xor(z, 32);
    float* zzz = lds + 64;
    if (lane < 8) zzz[wv * 8 + lane] = z;
    __syncthreads();
    if (tid < 8)
      ws[OFF_Z + tid] = zzz[tid] + zzz[8 + tid] + zzz[16 + tid] + zzz[24 + tid];
  }
}

// ---- kf: feat[c] = (y[c&7] . Wv[c,:]) / Z[c&7] + bv[c]  (wave per c) ----
__global__ __launch_bounds__(256) void kf(const float* __restrict__ Wv,
                                          const float* __restrict__ bv,
                                          float* __restrict__ ws) {
  int tid = threadIdx.x, lane = tid & 63;
  int c = blockIdx.x * 4 + (tid >> 6);
  int n = c & 7;
  const float4* yb = (const float4*)(ws + OFF_Y + n * MDIM);
  const float4* wb = (const float4*)(Wv + (size_t)c * MDIM);
  float acc = 0.f;
#pragma unroll
  for (int s = 0; s < 8; ++s) {
    int idx = s * 64 + lane;
    acc += dot4(yb[idx], wb[idx]);
  }
#pragma unroll
  for (int off = 32; off; off >>= 1) acc += __shfl_xor(acc, off);
  if (lane == 0) ws[OFF_FEAT + c] = acc / ws[OFF_Z + n] + bv[c];
}

// ---- ko: out[j] = relu(x.Wo[j,:1024] + feat.Wo[j,1024:] + bo[j]) (wave per j) ----
__global__ __launch_bounds__(256) void ko(const float* __restrict__ x,
                                          const float* __restrict__ Wo,
                                          const float* __restrict__ bo,
                                          const float* __restrict__ ws,
                                          float* __restrict__ out) {
  int tid = threadIdx.x, lane = tid & 63;
  int j = blockIdx.x * 4 + (tid >> 6);
  const float4* wb = (const float4*)(Wo + (size_t)j * 2048);
  const float4* xr = (const float4*)x;
  const float4* fr = (const float4*)(ws + OFF_FEAT);
  float acc = 0.f;
#pragma unroll
  for (int s = 0; s < 4; ++s) {
    int idx = s * 64 + lane;
    acc += dot4(xr[idx], wb[idx]);
    acc += dot4(fr[idx], wb[256 + idx]);
  }
#pragma unroll
  for (int off = 32; off; off >>= 1) acc += __shfl_xor(acc, off);
  if (lane == 0) out[j] = fmaxf(acc + bo[j], 0.f);
}

extern "C" void kernel_launch(void* const* d_in, const int* in_sizes, int n_in,
                              void* d_out, int out_size, void* d_ws, size_t ws_size,
                              hipStream_t stream) {
  const float* x   = (const float*)d_in[0];
  const float* mem = (const float*)d_in[1];
  const float* Wq  = (const float*)d_in[2];
  const float* bq  = (const float*)d_in[3];
  const float* Wk  = (const float*)d_in[4];
  const float* bk  = (const float*)d_in[5];
  const float* Wv  = (const float*)d_in[6];
  const float* bv  = (const float*)d_in[7];
  const float* Wo  = (const float*)d_in[8];
  const float* bo  = (const float*)d_in[9];
  float* ws  = (float*)d_ws;
  float* out = (float*)d_out;

  kq <<<256,  256, 0, stream>>>(x, Wq, bq, ws);
  kw <<<257,  256, 0, stream>>>(Wk, bk, ws);
  kA3<<<1024, 256, 0, stream>>>(mem, ws);
  kb <<<1024, 256, 0, stream>>>(mem, ws);
  ky <<<1024, 256, 0, stream>>>(ws);
  kf <<<256,  256, 0, stream>>>(Wv, bv, ws);
  ko <<<256,  256, 0, stream>>>(x, Wo, bo, ws, out);
}

// Round 6
// 262.877 us; speedup vs baseline: 3.8442x; 1.0420x over previous
//
#include <hip/hip_runtime.h>
#include <math.h>

#define HDIM  1024
#define MDIM  2048
#define RSQRT_D 0.08838834764831844f   // 1/sqrt(128)

// ---- workspace layout (float offsets), R4-proven ----
// Only w needs zeroing (kw atomics); kq zeroes it. Everything else full-write.
#define OFF_W     0          // w[8][2048]      (kw, atomic accum; zeroed by kq)
#define OFF_BETA  16384      // beta[8]         (kw block 256, non-atomic)
#define OFF_Z     16392      // Z[8]            (ky block 0, non-atomic)
#define OFF_Q     16400      // q[1024]         (kq)
#define OFF_FEAT  17424      // feat[1024]      (kf)
#define OFF_Y     18448      // y[8][2048]      (ky)
#define OFF_ZP    34832      // zpart[512][8]   (kab)
#define OFF_YBUF  301072     // ybuf[512][8][2048] (kab, 33.6 MB) -> end 34.8 MB

__device__ __forceinline__ float dot4(float4 a, float4 b) {
  return a.x * b.x + a.y * b.y + a.z * b.z + a.w * b.w;
}
__device__ __forceinline__ void fma4(float4& acc, float s, float4 v) {
  acc.x = fmaf(s, v.x, acc.x); acc.y = fmaf(s, v.y, acc.y);
  acc.z = fmaf(s, v.z, acc.z); acc.w = fmaf(s, v.w, acc.w);
}
__device__ __forceinline__ void add4(float4& a, float4 v) {
  a.x += v.x; a.y += v.y; a.z += v.z; a.w += v.w;
}

// ---- kq: q[j] = x.Wq[j,:] + bq[j] (wave per j); also zeroes w for kw's atomics ----
__global__ __launch_bounds__(256) void kq(const float* __restrict__ x,
                                          const float* __restrict__ Wq,
                                          const float* __restrict__ bq,
                                          float* __restrict__ ws) {
  int tid = threadIdx.x, lane = tid & 63;
  int j = blockIdx.x * 4 + (tid >> 6);
  const float4* xr = (const float4*)x;
  const float4* wr = (const float4*)(Wq + (size_t)j * HDIM);
  float acc = 0.f;
#pragma unroll
  for (int i = 0; i < 4; ++i) {
    int idx = i * 64 + lane;
    acc += dot4(xr[idx], wr[idx]);
  }
#pragma unroll
  for (int off = 32; off; off >>= 1) acc += __shfl_xor(acc, off);
  if (lane == 0) ws[OFF_Q + j] = acc + bq[j];
  // zero w slice: 16384 floats / 256 blocks = 64 per block
  if (tid < 64) ws[OFF_W + blockIdx.x * 64 + tid] = 0.f;
}

// ---- kw: w[n][m] += q[c]*Wk[c][m] (c-chunked atomics, grid 256);
//          block 256: beta[n] = sum_{c%8==n} q[c]*bk[c] (non-atomic) ----
__global__ __launch_bounds__(256) void kw(const float* __restrict__ Wk,
                                          const float* __restrict__ bk,
                                          float* __restrict__ ws) {
  __shared__ float lds[32];
  int tid = threadIdx.x;
  const float* q = ws + OFF_Q;
  if (blockIdx.x == 256) {   // beta block
    float b = 0.f;
#pragma unroll
    for (int i = 0; i < 4; ++i) {
      int c = tid + 256 * i;
      b = fmaf(q[c], bk[c], b);
    }
    b += __shfl_xor(b, 8); b += __shfl_xor(b, 16); b += __shfl_xor(b, 32);
    if ((tid & 63) < 8) lds[(tid >> 6) * 8 + (tid & 7)] = b;
    __syncthreads();
    if (tid < 8)
      ws[OFF_BETA + tid] = lds[tid] + lds[8 + tid] + lds[16 + tid] + lds[24 + tid];
    return;
  }
  int mc = blockIdx.x & 7, cc = blockIdx.x >> 3;   // 8 m-chunks x 32 c-chunks
  int m = mc * 256 + tid;
  float acc[8];
#pragma unroll
  for (int n = 0; n < 8; ++n) acc[n] = 0.f;
  int c0 = cc * 32;
#pragma unroll
  for (int cb = 0; cb < 32; cb += 8) {
#pragma unroll
    for (int u = 0; u < 8; ++u)
      acc[u] = fmaf(q[c0 + cb + u], Wk[(size_t)(c0 + cb + u) * MDIM + m], acc[u]);
  }
#pragma unroll
  for (int n = 0; n < 8; ++n) atomicAdd(&ws[OFF_W + n * MDIM + m], acc[n]);
}

// ---- kab: fused scores + softmax + weighted-sum. Grid 512 x 512 threads,
// LB(512,4) -> 2 blocks/CU (16 waves/CU). Block owns 32 rows x FULL 2048 cols,
// so scores complete in-block (no s2 handoff, no second mem-pass kernel).
// Phase A: wave owns 4 rows; per row: mva[4]/mvb[4] chunks + next-row prefetch,
// 8x{8 ds_read_b128 + 32 FMA} into acc[8] (register-lean R4-proven shape);
// butterfly; p=exp((acc+beta)*rsqrtd) -> pp; zacc. Phase B: kb-proven loop,
// rows re-read from L3 (just streamed). Writes ybuf[bid] + zpart[bid].
__global__ __launch_bounds__(512, 4) void kab(const float* __restrict__ mem,
                                              float* __restrict__ ws) {
  __shared__ float4 wlds[4096];            // w[8][2048] staged, 64 KB
  __shared__ __align__(16) float pp[256];  // p[32 rows][8 heads]
  __shared__ float zz[64];
  __shared__ float bb[8];
  int tid = threadIdx.x, lane = tid & 63, wv = tid >> 6;
  int bid = blockIdx.x;
  int r0 = bid * 32;

  const float4* wsrc = (const float4*)(ws + OFF_W);
#pragma unroll
  for (int k = 0; k < 8; ++k)
    wlds[k * 512 + tid] = wsrc[k * 512 + tid];
  if (tid < 8) bb[tid] = ws[OFF_BETA + tid];

  const float* rowp = mem + (size_t)(r0 + wv * 4) * MDIM;
  float4 mva[4], mvan[4], mvb[4];
#pragma unroll
  for (int i = 0; i < 4; ++i)
    mva[i] = *(const float4*)(rowp + (i * 64 + lane) * 4);
  __syncthreads();

  float zacc[8];
#pragma unroll
  for (int n = 0; n < 8; ++n) zacc[n] = 0.f;

#pragma unroll
  for (int rl = 0; rl < 4; ++rl) {
    // chunk1 (cols 1024..2047) of current row: issue early
#pragma unroll
    for (int i = 0; i < 4; ++i)
      mvb[i] = *(const float4*)(rowp + 1024 + (i * 64 + lane) * 4);
    float acc[8];
#pragma unroll
    for (int n = 0; n < 8; ++n) acc[n] = 0.f;
#pragma unroll
    for (int pass = 0; pass < 4; ++pass) {
      int cq = pass * 64 + lane;
#pragma unroll
      for (int n = 0; n < 8; ++n) {
        float4 w4 = wlds[n * 512 + cq];
        acc[n] = fmaf(mva[pass].x, w4.x, acc[n]);
        acc[n] = fmaf(mva[pass].y, w4.y, acc[n]);
        acc[n] = fmaf(mva[pass].z, w4.z, acc[n]);
        acc[n] = fmaf(mva[pass].w, w4.w, acc[n]);
      }
    }
    if (rl < 3) {   // prefetch next row's chunk0 under chunk1 compute + butterfly
#pragma unroll
      for (int i = 0; i < 4; ++i)
        mvan[i] = *(const float4*)(rowp + MDIM + (i * 64 + lane) * 4);
    }
#pragma unroll
    for (int pass = 0; pass < 4; ++pass) {
      int cq = 256 + pass * 64 + lane;
#pragma unroll
      for (int n = 0; n < 8; ++n) {
        float4 w4 = wlds[n * 512 + cq];
        acc[n] = fmaf(mvb[pass].x, w4.x, acc[n]);
        acc[n] = fmaf(mvb[pass].y, w4.y, acc[n]);
        acc[n] = fmaf(mvb[pass].z, w4.z, acc[n]);
        acc[n] = fmaf(mvb[pass].w, w4.w, acc[n]);
      }
    }
#pragma unroll
    for (int off = 1; off < 64; off <<= 1)
#pragma unroll
      for (int n = 0; n < 8; ++n)
        acc[n] += __shfl_xor(acc[n], off);
#pragma unroll
    for (int n = 0; n < 8; ++n) {
      float p = __expf((acc[n] + bb[n]) * RSQRT_D);
      zacc[n] += p;
      if (lane == 0) pp[(wv * 4 + rl) * 8 + n] = p;
    }
#pragma unroll
    for (int i = 0; i < 4; ++i) mva[i] = mvan[i];
    rowp += MDIM;
  }
  if (lane == 0) {
#pragma unroll
    for (int n = 0; n < 8; ++n) zz[wv * 8 + n] = zacc[n];
  }
  __syncthreads();
  if (tid < 8) {
    float z = 0.f;
#pragma unroll
    for (int w = 0; w < 8; ++w) z += zz[w * 8 + tid];
    ws[OFF_ZP + bid * 8 + tid] = z;
  }

  // ---- phase B: y += p * mem for the same 32 rows (L3-hot re-read) ----
  float4 acc4[8];
#pragma unroll
  for (int n = 0; n < 8; ++n) acc4[n] = make_float4(0.f, 0.f, 0.f, 0.f);
  const float* base = mem + (size_t)r0 * MDIM + tid * 4;
  const float4* pp4 = (const float4*)pp;
#pragma unroll 4
  for (int r = 0; r < 32; ++r) {
    float4 mv = *(const float4*)(base + (size_t)r * MDIM);
    float4 pA = pp4[r * 2], pB = pp4[r * 2 + 1];   // broadcast
    fma4(acc4[0], pA.x, mv); fma4(acc4[1], pA.y, mv);
    fma4(acc4[2], pA.z, mv); fma4(acc4[3], pA.w, mv);
    fma4(acc4[4], pB.x, mv); fma4(acc4[5], pB.y, mv);
    fma4(acc4[6], pB.z, mv); fma4(acc4[7], pB.w, mv);
  }
  float* yb = ws + OFF_YBUF + (size_t)bid * 16384 + tid * 4;
#pragma unroll
  for (int n = 0; n < 8; ++n)
    *(float4*)(yb + n * MDIM) = acc4[n];
}

// ---- ky: y[quad] = sum_b ybuf[b][quad]; block 0 reduces Z. Grid 1024. ----
__global__ __launch_bounds__(256) void ky(float* __restrict__ ws) {
  __shared__ __align__(16) float lds[96];
  int tid = threadIdx.x, lane = tid & 63, wv = tid >> 6;
  int bid = blockIdx.x;
  const float4* src = (const float4*)(ws + OFF_YBUF);
  int qd = bid * 4 + (tid & 3);
  int h = tid >> 2;                  // 0..63
  float4 a = make_float4(0.f, 0.f, 0.f, 0.f);
#pragma unroll
  for (int i = 0; i < 8; ++i)
    add4(a, src[(size_t)(h + 64 * i) * 4096 + qd]);
#pragma unroll
  for (int off = 4; off < 64; off <<= 1) {
    a.x += __shfl_xor(a.x, off);
    a.y += __shfl_xor(a.y, off);
    a.z += __shfl_xor(a.z, off);
    a.w += __shfl_xor(a.w, off);
  }
  float4* sq = (float4*)lds;         // 16 float4
  if (lane < 4) sq[wv * 4 + lane] = a;
  __syncthreads();
  if (tid < 4) {
    float4 s = sq[tid];
    add4(s, sq[4 + tid]); add4(s, sq[8 + tid]); add4(s, sq[12 + tid]);
    ((float4*)(ws + OFF_Y))[bid * 4 + tid] = s;
  }
  if (bid == 0) {   // Z[n] = sum_b zpart[b][n]
    int n = tid & 7;
    float z = 0.f;
#pragma unroll
    for (int i = 0; i < 16; ++i)
      z += ws[OFF_ZP + ((tid >> 3) + 32 * i) * 8 + n];
    z += __shfl_xor(z, 8); z += __shfl_xor(z, 16); z += __shfl_xor(z, 32);
    float* zzz = lds + 64;
    if (lane < 8) zzz[wv * 8 + lane] = z;
    __syncthreads();
    if (tid < 8)
      ws[OFF_Z + tid] = zzz[tid] + zzz[8 + tid] + zzz[16 + tid] + zzz[24 + tid];
  }
}

// ---- kf: feat[c] = (y[c&7] . Wv[c,:]) / Z[c&7] + bv[c]  (wave per c) ----
__global__ __launch_bounds__(256) void kf(const float* __restrict__ Wv,
                                          const float* __restrict__ bv,
                                          float* __restrict__ ws) {
  int tid = threadIdx.x, lane = tid & 63;
  int c = blockIdx.x * 4 + (tid >> 6);
  int n = c & 7;
  const float4* yb = (const float4*)(ws + OFF_Y + n * MDIM);
  const float4* wb = (const float4*)(Wv + (size_t)c * MDIM);
  float acc = 0.f;
#pragma unroll
  for (int s = 0; s < 8; ++s) {
    int idx = s * 64 + lane;
    acc += dot4(yb[idx], wb[idx]);
  }
#pragma unroll
  for (int off = 32; off; off >>= 1) acc += __shfl_xor(acc, off);
  if (lane == 0) ws[OFF_FEAT + c] = acc / ws[OFF_Z + n] + bv[c];
}

// ---- ko: out[j] = relu(x.Wo[j,:1024] + feat.Wo[j,1024:] + bo[j]) (wave per j) ----
__global__ __launch_bounds__(256) void ko(const float* __restrict__ x,
                                          const float* __restrict__ Wo,
                                          const float* __restrict__ bo,
                                          const float* __restrict__ ws,
                                          float* __restrict__ out) {
  int tid = threadIdx.x, lane = tid & 63;
  int j = blockIdx.x * 4 + (tid >> 6);
  const float4* wb = (const float4*)(Wo + (size_t)j * 2048);
  const float4* xr = (const float4*)x;
  const float4* fr = (const float4*)(ws + OFF_FEAT);
  float acc = 0.f;
#pragma unroll
  for (int s = 0; s < 4; ++s) {
    int idx = s * 64 + lane;
    acc += dot4(xr[idx], wb[idx]);
    acc += dot4(fr[idx], wb[256 + idx]);
  }
#pragma unroll
  for (int off = 32; off; off >>= 1) acc += __shfl_xor(acc, off);
  if (lane == 0) out[j] = fmaxf(acc + bo[j], 0.f);
}

extern "C" void kernel_launch(void* const* d_in, const int* in_sizes, int n_in,
                              void* d_out, int out_size, void* d_ws, size_t ws_size,
                              hipStream_t stream) {
  const float* x   = (const float*)d_in[0];
  const float* mem = (const float*)d_in[1];
  const float* Wq  = (const float*)d_in[2];
  const float* bq  = (const float*)d_in[3];
  const float* Wk  = (const float*)d_in[4];
  const float* bk  = (const float*)d_in[5];
  const float* Wv  = (const float*)d_in[6];
  const float* bv  = (const float*)d_in[7];
  const float* Wo  = (const float*)d_in[8];
  const float* bo  = (const float*)d_in[9];
  float* ws  = (float*)d_ws;
  float* out = (float*)d_out;

  kq <<<256, 256, 0, stream>>>(x, Wq, bq, ws);
  kw <<<257, 256, 0, stream>>>(Wk, bk, ws);
  kab<<<512, 512, 0, stream>>>(mem, ws);
  ky <<<1024, 256, 0, stream>>>(ws);
  kf <<<256, 256, 0, stream>>>(Wv, bv, ws);
  ko <<<256, 256, 0, stream>>>(x, Wo, bo, ws, out);
}